// Round 10
// baseline (282.267 us; speedup 1.0000x reference)
//
#include <hip/hip_runtime.h>

#define DIMQ 1024
#define NH 4
#define HD 256
#define BSZ 4
#define LQ 2048
#define LKV 2048
#define KSTR 1024           // kp row stride
#define VSTR (BSZ * LKV)    // vpT row stride (batch-interleaved cols)

typedef __attribute__((ext_vector_type(8))) short bf16x8;
typedef __attribute__((ext_vector_type(4))) float f32x4;

__device__ inline unsigned short f32_to_bf16(float f) {
  union { float f; unsigned u; } v; v.f = f;
  unsigned u = v.u;
  return (unsigned short)((u + 0x7fffu + ((u >> 16) & 1u)) >> 16);
}

__device__ inline uint4 ld8cvt(const float* p, float scale) {
  const float4 a = *(const float4*)p;
  const float4 b = *(const float4*)(p + 4);
  union { unsigned short s[8]; uint4 v; } r;
  r.s[0] = f32_to_bf16(a.x * scale); r.s[1] = f32_to_bf16(a.y * scale);
  r.s[2] = f32_to_bf16(a.z * scale); r.s[3] = f32_to_bf16(a.w * scale);
  r.s[4] = f32_to_bf16(b.x * scale); r.s[5] = f32_to_bf16(b.y * scale);
  r.s[6] = f32_to_bf16(b.z * scale); r.s[7] = f32_to_bf16(b.w * scale);
  return r.v;
}

// async global->LDS, 16 B per lane; lds dest must be wave-uniform base.
__device__ __forceinline__ void gl2lds16(const void* gptr, void* lptr) {
  __builtin_amdgcn_global_load_lds(
      (const __attribute__((address_space(1))) void*)gptr,
      (__attribute__((address_space(3))) void*)lptr, 16, 0, 0);
}

// fp32 -> bf16 conversion (with per-segment scale), up to 6 segments.
__global__ __launch_bounds__(256)
void cvt6(const float* s0, const float* s1, const float* s2, const float* s3,
          const float* s4, const float* s5,
          unsigned short* d0, unsigned short* d1, unsigned short* d2,
          unsigned short* d3, unsigned short* d4, unsigned short* d5,
          long n0, long n1, long n2, long n3, long n4, long n5,
          float c0, float c1, float c2, float c3, float c4, float c5) {
  const float* s; unsigned short* d; long n; float c;
  switch (blockIdx.y) {
    case 0: s = s0; d = d0; n = n0; c = c0; break;
    case 1: s = s1; d = d1; n = n1; c = c1; break;
    case 2: s = s2; d = d2; n = n2; c = c2; break;
    case 3: s = s3; d = d3; n = n3; c = c3; break;
    case 4: s = s4; d = d4; n = n4; c = c4; break;
    default: s = s5; d = d5; n = n5; c = c5; break;
  }
  long i = ((long)blockIdx.x * 256 + threadIdx.x) * 8;
  if (i < n) *(uint4*)(d + i) = ld8cvt(s + i, c);
}

// C[m,n] = sum_k A[m,k]*B[n,k] (+bias); bf16 in, fp32 acc.
// R9-verified: single-barrier double-buffered K-loop + T2 LDS swizzle
// (16B slot ^= row&7, both-sides: pre-swizzled global source col
// (scol^srow)<<3 for the DMA, swizzled slot index on ds_read).
// 1D grid, XCD-bijective swizzle (nwg%8==0 for all calls). 2 blocks/CU.
template<typename TOUT, bool HAS_BIAS>
__global__ __launch_bounds__(256)
void gemm_bt(const unsigned short* __restrict__ A,
             const unsigned short* __restrict__ Bm,
             const float* __restrict__ bias,
             TOUT* __restrict__ C,
             int M, int N, int K) {
  __shared__ alignas(16) unsigned short As[2][128 * 64];
  __shared__ alignas(16) unsigned short Bs[2][128 * 64];
  const int tid = threadIdx.x;
  const int lane = tid & 63;
  const int wave = tid >> 6;
  const int wr = (wave >> 1) * 64, wc = (wave & 1) * 64;
  const int l15 = lane & 15, quad = lane >> 4;
  const int srow = lane >> 3, scol = lane & 7;
  const int ny = N >> 7;
  const int nwg = (M >> 7) * ny;
  const int cpx = nwg >> 3;
  const int lin = blockIdx.x;
  const int wid = (lin & 7) * cpx + (lin >> 3);   // XCD-contiguous remap
  const int m0 = (wid / ny) << 7;
  const int n0 = (wid % ny) << 7;
  const int scs = (scol ^ srow) << 3;             // pre-swizzled source col

  auto stage = [&](int k0, int buf) {
#pragma unroll
    for (int i = 0; i < 4; ++i) {
      int c = wave * 4 + i;
      gl2lds16(A + (size_t)(m0 + c * 8 + srow) * K + k0 + scs, As[buf] + c * 512);
      gl2lds16(Bm + (size_t)(n0 + c * 8 + srow) * K + k0 + scs, Bs[buf] + c * 512);
    }
  };

  f32x4 acc[4][4] = {};
  const int nk = K >> 6;
  stage(0, 0);
  for (int t = 0; t < nk; ++t) {
    __syncthreads();                       // drains stage(t)
    if (t + 1 < nk) stage((t + 1) << 6, (t + 1) & 1);
    const unsigned short* Ac = As[t & 1];
    const unsigned short* Bc = Bs[t & 1];
#pragma unroll
    for (int kh = 0; kh < 2; ++kh) {
      bf16x8 af[4], bfr[4];
#pragma unroll
      for (int i = 0; i < 4; ++i) {
        int ar = wr + i * 16 + l15;
        af[i] = *(const bf16x8*)(Ac + ar * 64 + (((kh * 4 + quad) ^ (ar & 7)) << 3));
      }
#pragma unroll
      for (int j = 0; j < 4; ++j) {
        int br = wc + j * 16 + l15;
        bfr[j] = *(const bf16x8*)(Bc + br * 64 + (((kh * 4 + quad) ^ (br & 7)) << 3));
      }
#pragma unroll
      for (int i = 0; i < 4; ++i)
#pragma unroll
        for (int j = 0; j < 4; ++j)
          acc[i][j] = __builtin_amdgcn_mfma_f32_16x16x32_bf16(af[i], bfr[j], acc[i][j], 0, 0, 0);
    }
  }

#pragma unroll
  for (int j = 0; j < 4; ++j) {
    int n = n0 + wc + j * 16 + l15;
    float bv = 0.f;
    if (HAS_BIAS) bv = bias[n];
#pragma unroll
    for (int i = 0; i < 4; ++i) {
      int mb = m0 + wr + i * 16 + quad * 4;
#pragma unroll
      for (int r = 0; r < 4; ++r) {
        float v = acc[i][j][r] + bv;
        if constexpr (sizeof(TOUT) == 2)
          C[(size_t)(mb + r) * N + n] = f32_to_bf16(v);
        else
          C[(size_t)(mb + r) * N + n] = v;
      }
    }
  }
}

// Flash attention, KV tile 64 (R3-verified structure: ~94 us).
//   Inputs now: kp [BSZ*LKV][KSTR=1024] (K-proj only) and vpT [DIMQ][VSTR=8192]
//   (V^T computed DIRECTLY by a gemm_bt call: vpT[d][b*2048+l] = vp[l][d];
//   transpose kernel eliminated). Only the two staging address formulas
//   changed vs R9; LDS layouts/swizzles identical.
__global__ __launch_bounds__(256, 2)
void attn(const unsigned short* __restrict__ qp,
          const unsigned short* __restrict__ kp,
          const unsigned short* __restrict__ vpT,
          unsigned short* __restrict__ ctx) {
  __shared__ alignas(16) unsigned short Ks[64 * 256];
  __shared__ alignas(16) unsigned short Vt[256 * 64];
  __shared__ alignas(16) unsigned short Ps[64 * 64];
  __shared__ float Ls[64][2];                              // per-row partial sums
  const int tid = threadIdx.x, lane = tid & 63, wave = tid >> 6;
  const int l15 = lane & 15, quad = lane >> 4;
  const int qh = wave >> 1;        // q half (QK)
  const int kvh = wave & 1;        // kv half (QK)
  const int lin = blockIdx.x;
  const int work = ((lin & 7) << 6) + (lin >> 3);   // XCD-contiguous remap
  const int b = work >> 7, h = (work >> 5) & 3;
  const int q0 = (work & 31) * 64;
  const size_t base = (size_t)b * LQ * DIMQ + h * HD;

  // Q fragments, 2 m-tiles: A[m=l15][k=quad*8+j], rows qh*32+im*16+l15
  bf16x8 qf[2][8];
#pragma unroll
  for (int im = 0; im < 2; ++im) {
    const unsigned short* qrow =
        qp + base + (size_t)(q0 + qh * 32 + im * 16 + l15) * DIMQ;
#pragma unroll
    for (int s = 0; s < 8; ++s)
      qf[im][s] = *(const bf16x8*)(qrow + s * 32 + quad * 8);
  }

  f32x4 oacc[4][4] = {};   // O rows mt*16+quad*4+r, cols wave*64+nt*16+l15
  float lrow[2][4] = {};

  const unsigned short* kb = kp + (size_t)b * LKV * KSTR + h * HD;   // stride KSTR
  const unsigned short* vtb = vpT + (size_t)(h * HD) * VSTR + (size_t)b * LKV;

  const int krow_l = lane >> 5;   // K stage: 2 rows (512B) per 1KB chunk
  const int kcol_l = lane & 31;
  const int vrow_l = lane >> 3;   // V stage: 8 rows (128B) per 1KB chunk
  const int vcol_l = lane & 7;

  // prologue: stage K tile 0 (row-permuted source)
#pragma unroll
  for (int i = 0; i < 8; ++i) {
    int c = i * 4 + wave;
    int row = 2 * c + krow_l;                                  // LDS row
    int lr = (row & 32) + ((row & 15) << 1) + ((row >> 4) & 1); // logical kv
    gl2lds16(kb + (size_t)lr * KSTR + ((kcol_l ^ (row & 7)) << 3), Ks + c * 512);
  }
  __syncthreads();

  for (int kv0 = 0; kv0 < LKV; kv0 += 64) {
    // stage V(t): latency hides under QK + softmax
#pragma unroll
    for (int i = 0; i < 8; ++i) {
      int c = i * 4 + wave;
      int row = 8 * c + vrow_l;
      gl2lds16(vtb + (size_t)row * VSTR + kv0 + ((vcol_l ^ (row & 7)) << 3),
               Vt + c * 512);
    }

    // QK: S 32q x 32kv per wave (2m x 2n), Q from regs
    f32x4 sacc[2][2] = {};
    const int r0 = kvh * 32 + l15, r1 = r0 + 16;
    __builtin_amdgcn_s_setprio(1);
#pragma unroll
    for (int s = 0; s < 8; ++s) {
      bf16x8 kf0 = *(const bf16x8*)(Ks + r0 * 256 + (((s * 4 + quad) ^ (r0 & 7)) << 3));
      bf16x8 kf1 = *(const bf16x8*)(Ks + r1 * 256 + (((s * 4 + quad) ^ (r1 & 7)) << 3));
      sacc[0][0] = __builtin_amdgcn_mfma_f32_16x16x32_bf16(qf[0][s], kf0, sacc[0][0], 0, 0, 0);
      sacc[0][1] = __builtin_amdgcn_mfma_f32_16x16x32_bf16(qf[0][s], kf1, sacc[0][1], 0, 0, 0);
      sacc[1][0] = __builtin_amdgcn_mfma_f32_16x16x32_bf16(qf[1][s], kf0, sacc[1][0], 0, 0, 0);
      sacc[1][1] = __builtin_amdgcn_mfma_f32_16x16x32_bf16(qf[1][s], kf1, sacc[1][1], 0, 0, 0);
    }
    __builtin_amdgcn_s_setprio(0);

    // p = exp2(s); sacc[..][0]=col 2*l15, sacc[..][1]=col 2*l15+1 (adjacent)
    // -> one packed dword write per (im,i).
    const int dw = kvh * 16 + l15;       // dword index within row
    const int t16 = dw >> 2, sub = dw & 3;
#pragma unroll
    for (int im = 0; im < 2; ++im)
#pragma unroll
      for (int i = 0; i < 4; ++i) {
        int row = qh * 32 + im * 16 + quad * 4 + i;
        float p0 = exp2f(sacc[im][0][i]);
        float p1 = exp2f(sacc[im][1][i]);
        unsigned pw = (unsigned)f32_to_bf16(p0) | ((unsigned)f32_to_bf16(p1) << 16);
        *(unsigned*)(Ps + row * 64 + (((t16 ^ (row & 7)) << 3) | (sub * 2))) = pw;
        lrow[im][i] += p0 + p1;
      }
    __syncthreads();   // V(t) staged + P visible block-wide

    // stage K(t+1): latency hides under PV (row-permuted source)
    if (kv0 + 64 < LKV) {
#pragma unroll
      for (int i = 0; i < 8; ++i) {
        int c = i * 4 + wave;
        int row = 2 * c + krow_l;
        int lr = (row & 32) + ((row & 15) << 1) + ((row >> 4) & 1);
        gl2lds16(kb + (size_t)(kv0 + 64 + lr) * KSTR + ((kcol_l ^ (row & 7)) << 3),
                 Ks + c * 512);
      }
    }

    // PV: O 64q x 64d per wave (4m x 4n), every fragment feeds 4 MFMAs
    __builtin_amdgcn_s_setprio(1);
#pragma unroll
    for (int u = 0; u < 2; ++u) {
      bf16x8 pf[4], vf[4];
#pragma unroll
      for (int mt = 0; mt < 4; ++mt) {
        int pr = mt * 16 + l15;
        pf[mt] = *(const bf16x8*)(Ps + pr * 64 + (((u * 4 + quad) ^ (pr & 7)) << 3));
      }
#pragma unroll
      for (int nt = 0; nt < 4; ++nt) {
        int vr = wave * 64 + nt * 16 + l15;
        vf[nt] = *(const bf16x8*)(Vt + vr * 64 + (((u * 4 + quad) ^ (vr & 7)) << 3));
      }
#pragma unroll
      for (int mt = 0; mt < 4; ++mt)
#pragma unroll
        for (int nt = 0; nt < 4; ++nt)
          oacc[mt][nt] = __builtin_amdgcn_mfma_f32_16x16x32_bf16(pf[mt], vf[nt], oacc[mt][nt], 0, 0, 0);
    }
    __builtin_amdgcn_s_setprio(0);
    __syncthreads();   // K(t+1) staged; PV readers done
  }

  // epilogue: reduce l over l15 lanes, then cross-wave (kv halves) via Ls
#pragma unroll
  for (int im = 0; im < 2; ++im)
#pragma unroll
    for (int i = 0; i < 4; ++i) {
      float l = lrow[im][i];
      l += __shfl_xor(l, 1);
      l += __shfl_xor(l, 2);
      l += __shfl_xor(l, 4);
      l += __shfl_xor(l, 8);
      if (l15 == 0) Ls[qh * 32 + im * 16 + quad * 4 + i][kvh] = l;
    }
  __syncthreads();

  unsigned short* cb = ctx + base;
#pragma unroll
  for (int mt = 0; mt < 4; ++mt)
#pragma unroll
    for (int r = 0; r < 4; ++r) {
      int row = mt * 16 + quad * 4 + r;
      float inv = 1.0f / (Ls[row][0] + Ls[row][1]);
#pragma unroll
      for (int nt = 0; nt < 4; ++nt) {
        int col = wave * 64 + nt * 16 + l15;
        cb[(size_t)(q0 + row) * DIMQ + col] = f32_to_bf16(oacc[mt][nt][r] * inv);
      }
    }
}

extern "C" void kernel_launch(void* const* d_in, const int* in_sizes, int n_in,
                              void* d_out, int out_size, void* d_ws, size_t ws_size,
                              hipStream_t stream) {
  const float* q  = (const float*)d_in[0];
  const float* kv = (const float*)d_in[1];
  const float* Wq = (const float*)d_in[2];
  const float* Wk = (const float*)d_in[3];
  const float* Wv = (const float*)d_in[4];
  const float* Wo = (const float*)d_in[5];
  const float* bo = (const float*)d_in[6];
  float* out = (float*)d_out;

  const long NQ = (long)BSZ * LQ * DIMQ;       // 8388608
  const long NKV = (long)BSZ * LKV * 768;      // 6291456
  const long NWQ = (long)DIMQ * DIMQ;          // 1048576
  const long NWK = (long)DIMQ * 768;           // 786432

  // d_out phases: q_bf (16 MB) -> kp [8192][1024] (16 MB, overwrites q_bf
  // after qp GEMM) -> final fp32 out (32 MB, after attn).
  unsigned short* q_bf = (unsigned short*)d_out;
  unsigned short* kp   = (unsigned short*)d_out;
  // ws (58 MB): [kv_bf|ctx 16MB][Wq 2][Wk 1.5][Wv 1.5][Wo 2][qp 16][vpT 16]
  unsigned short* kv_bf = (unsigned short*)d_ws;
  unsigned short* ctx   = kv_bf;                           // kv_bf dead after vpT GEMM
  unsigned short* Wq_bf = kv_bf + NQ;
  unsigned short* Wk_bf = Wq_bf + NWQ;
  unsigned short* Wv_bf = Wk_bf + NWK;
  unsigned short* Wo_bf = Wv_bf + NWK;
  unsigned short* qp    = Wo_bf + NWQ;
  unsigned short* vpT   = qp + NQ;               // [DIMQ][BSZ*LKV] = 16 MB

  dim3 blk(256);
  const int M = BSZ * LQ;  // 8192

  // 1) convert q + kv + weights. Wq scale folds 1/16 (sqrt(hd)) AND log2(e)
  //    (softmax computed in exp2 domain).
  cvt6<<<dim3(4096, 6), blk, 0, stream>>>(
      kv, Wq, Wk, Wv, Wo, q,
      kv_bf, Wq_bf, Wk_bf, Wv_bf, Wo_bf, q_bf,
      NKV, NWQ, NWK, NWK, NWQ, NQ,
      1.0f, 0.0625f * 1.44269504088896f, 1.0f, 1.0f, 1.0f, 1.0f);
  // 2) qp = q_bf Wq^T (reads d_out, writes ws). nwg=512.
  gemm_bt<unsigned short, false><<<dim3((M/128)*(DIMQ/128)), blk, 0, stream>>>(q_bf, Wq_bf, nullptr, qp, M, DIMQ, 1024);
  // 3) kp = kv_bf Wk^T (overwrites q_bf - dead). nwg=512.
  gemm_bt<unsigned short, false><<<dim3((M/128)*(DIMQ/128)), blk, 0, stream>>>(kv_bf, Wk_bf, nullptr, kp, M, DIMQ, 768);
  // 4) vpT = Wv kv_bf^T  -> V^T directly (replaces transpose kernel):
  //    vpT[d][b*2048+l] = sum_k Wv[d,k] kv_bf[b*2048+l,k]. M=1024,N=8192,nwg=512.
  gemm_bt<unsigned short, false><<<dim3((DIMQ/128)*(M/128)), blk, 0, stream>>>(Wv_bf, kv_bf, nullptr, vpT, DIMQ, M, 768);
  // 5) attention -> ctx (kv_bf slot, dead)
  attn<<<dim3(512), blk, 0, stream>>>(qp, kp, vpT, ctx);
  // 6) out = ctx Wo^T + bo (fp32, overwrites kp - dead)
  gemm_bt<float, true><<<dim3((M/128)*(DIMQ/128)), blk, 0, stream>>>(ctx, Wo_bf, bo, out, M, DIMQ, 1024);
}

// Round 11
// 279.938 us; speedup vs baseline: 1.0083x; 1.0083x over previous
//
#include <hip/hip_runtime.h>

#define DIMQ 1024
#define NH 4
#define HD 256
#define BSZ 4
#define LQ 2048
#define LKV 2048
#define KSTR 1024           // kp row stride

typedef __attribute__((ext_vector_type(8))) short bf16x8;
typedef __attribute__((ext_vector_type(4))) float f32x4;

__device__ inline unsigned short f32_to_bf16(float f) {
  union { float f; unsigned u; } v; v.f = f;
  unsigned u = v.u;
  return (unsigned short)((u + 0x7fffu + ((u >> 16) & 1u)) >> 16);
}

__device__ inline uint4 ld8cvt(const float* p, float scale) {
  const float4 a = *(const float4*)p;
  const float4 b = *(const float4*)(p + 4);
  union { unsigned short s[8]; uint4 v; } r;
  r.s[0] = f32_to_bf16(a.x * scale); r.s[1] = f32_to_bf16(a.y * scale);
  r.s[2] = f32_to_bf16(a.z * scale); r.s[3] = f32_to_bf16(a.w * scale);
  r.s[4] = f32_to_bf16(b.x * scale); r.s[5] = f32_to_bf16(b.y * scale);
  r.s[6] = f32_to_bf16(b.z * scale); r.s[7] = f32_to_bf16(b.w * scale);
  return r.v;
}

// async global->LDS, 16 B per lane; lds dest must be wave-uniform base.
__device__ __forceinline__ void gl2lds16(const void* gptr, void* lptr) {
  __builtin_amdgcn_global_load_lds(
      (const __attribute__((address_space(1))) void*)gptr,
      (__attribute__((address_space(3))) void*)lptr, 16, 0, 0);
}

// fp32 -> bf16 conversion (with per-segment scale), up to 6 segments.
__global__ __launch_bounds__(256)
void cvt6(const float* s0, const float* s1, const float* s2, const float* s3,
          const float* s4, const float* s5,
          unsigned short* d0, unsigned short* d1, unsigned short* d2,
          unsigned short* d3, unsigned short* d4, unsigned short* d5,
          long n0, long n1, long n2, long n3, long n4, long n5,
          float c0, float c1, float c2, float c3, float c4, float c5) {
  const float* s; unsigned short* d; long n; float c;
  switch (blockIdx.y) {
    case 0: s = s0; d = d0; n = n0; c = c0; break;
    case 1: s = s1; d = d1; n = n1; c = c1; break;
    case 2: s = s2; d = d2; n = n2; c = c2; break;
    case 3: s = s3; d = d3; n = n3; c = c3; break;
    case 4: s = s4; d = d4; n = n4; c = c4; break;
    default: s = s5; d = d5; n = n5; c = c5; break;
  }
  long i = ((long)blockIdx.x * 256 + threadIdx.x) * 8;
  if (i < n) *(uint4*)(d + i) = ld8cvt(s + i, c);
}

// C[m,n] = sum_k A[m,k]*B[n,k] (+bias); bf16 in, fp32 acc.
// R9-verified: single-barrier double-buffered K-loop + T2 LDS swizzle
// (16B slot ^= row&7, both-sides: pre-swizzled global source col
// (scol^srow)<<3 for the DMA, swizzled slot index on ds_read).
// BATCH_OUT epilogue (vpT GEMM only): store C[m][n] at
// (n>>11)*2^21 + m*2048 + (n&2047)  ->  vpT[b][d][l], the R3-verified
// batch-blocked V^T layout (R10 lesson: flat [d][8192] broke attn's
// V-staging L2 locality, +5us).
// 1D grid, XCD-bijective swizzle (nwg%8==0 for all calls). 2 blocks/CU.
template<typename TOUT, bool HAS_BIAS, bool BATCH_OUT = false>
__global__ __launch_bounds__(256)
void gemm_bt(const unsigned short* __restrict__ A,
             const unsigned short* __restrict__ Bm,
             const float* __restrict__ bias,
             TOUT* __restrict__ C,
             int M, int N, int K) {
  __shared__ alignas(16) unsigned short As[2][128 * 64];
  __shared__ alignas(16) unsigned short Bs[2][128 * 64];
  const int tid = threadIdx.x;
  const int lane = tid & 63;
  const int wave = tid >> 6;
  const int wr = (wave >> 1) * 64, wc = (wave & 1) * 64;
  const int l15 = lane & 15, quad = lane >> 4;
  const int srow = lane >> 3, scol = lane & 7;
  const int ny = N >> 7;
  const int nwg = (M >> 7) * ny;
  const int cpx = nwg >> 3;
  const int lin = blockIdx.x;
  const int wid = (lin & 7) * cpx + (lin >> 3);   // XCD-contiguous remap
  const int m0 = (wid / ny) << 7;
  const int n0 = (wid % ny) << 7;
  const int scs = (scol ^ srow) << 3;             // pre-swizzled source col

  auto stage = [&](int k0, int buf) {
#pragma unroll
    for (int i = 0; i < 4; ++i) {
      int c = wave * 4 + i;
      gl2lds16(A + (size_t)(m0 + c * 8 + srow) * K + k0 + scs, As[buf] + c * 512);
      gl2lds16(Bm + (size_t)(n0 + c * 8 + srow) * K + k0 + scs, Bs[buf] + c * 512);
    }
  };

  f32x4 acc[4][4] = {};
  const int nk = K >> 6;
  stage(0, 0);
  for (int t = 0; t < nk; ++t) {
    __syncthreads();                       // drains stage(t)
    if (t + 1 < nk) stage((t + 1) << 6, (t + 1) & 1);
    const unsigned short* Ac = As[t & 1];
    const unsigned short* Bc = Bs[t & 1];
#pragma unroll
    for (int kh = 0; kh < 2; ++kh) {
      bf16x8 af[4], bfr[4];
#pragma unroll
      for (int i = 0; i < 4; ++i) {
        int ar = wr + i * 16 + l15;
        af[i] = *(const bf16x8*)(Ac + ar * 64 + (((kh * 4 + quad) ^ (ar & 7)) << 3));
      }
#pragma unroll
      for (int j = 0; j < 4; ++j) {
        int br = wc + j * 16 + l15;
        bfr[j] = *(const bf16x8*)(Bc + br * 64 + (((kh * 4 + quad) ^ (br & 7)) << 3));
      }
#pragma unroll
      for (int i = 0; i < 4; ++i)
#pragma unroll
        for (int j = 0; j < 4; ++j)
          acc[i][j] = __builtin_amdgcn_mfma_f32_16x16x32_bf16(af[i], bfr[j], acc[i][j], 0, 0, 0);
    }
  }

#pragma unroll
  for (int j = 0; j < 4; ++j) {
    int n = n0 + wc + j * 16 + l15;
    float bv = 0.f;
    if (HAS_BIAS) bv = bias[n];
#pragma unroll
    for (int i = 0; i < 4; ++i) {
      int mb = m0 + wr + i * 16 + quad * 4;
#pragma unroll
      for (int r = 0; r < 4; ++r) {
        float v = acc[i][j][r] + bv;
        if constexpr (BATCH_OUT) {
          // vpT[b][d][l]: b = n>>11, d = mb+r, l = n&2047
          C[((size_t)(n >> 11) << 21) + (size_t)(mb + r) * 2048 + (n & 2047)] =
              f32_to_bf16(v);
        } else if constexpr (sizeof(TOUT) == 2) {
          C[(size_t)(mb + r) * N + n] = f32_to_bf16(v);
        } else {
          C[(size_t)(mb + r) * N + n] = v;
        }
      }
    }
  }
}

// Flash attention, KV tile 64 (R3-verified structure: ~94 us).
//   Inputs: kp [BSZ*LKV][KSTR=1024] (K-proj only) and vpT [BSZ][DIMQ][LKV]
//   (batch-blocked V^T, written directly by the BATCH_OUT GEMM -- identical
//   layout to the R3/R9 transpose output; transpose kernel eliminated).
//   V addressing is R3-exact; only K's row stride differs (1024 vs 2048).
__global__ __launch_bounds__(256, 2)
void attn(const unsigned short* __restrict__ qp,
          const unsigned short* __restrict__ kp,
          const unsigned short* __restrict__ vpT,
          unsigned short* __restrict__ ctx) {
  __shared__ alignas(16) unsigned short Ks[64 * 256];
  __shared__ alignas(16) unsigned short Vt[256 * 64];
  __shared__ alignas(16) unsigned short Ps[64 * 64];
  __shared__ float Ls[64][2];                              // per-row partial sums
  const int tid = threadIdx.x, lane = tid & 63, wave = tid >> 6;
  const int l15 = lane & 15, quad = lane >> 4;
  const int qh = wave >> 1;        // q half (QK)
  const int kvh = wave & 1;        // kv half (QK)
  const int lin = blockIdx.x;
  const int work = ((lin & 7) << 6) + (lin >> 3);   // XCD-contiguous remap
  const int b = work >> 7, h = (work >> 5) & 3;
  const int q0 = (work & 31) * 64;
  const size_t base = (size_t)b * LQ * DIMQ + h * HD;

  // Q fragments, 2 m-tiles: A[m=l15][k=quad*8+j], rows qh*32+im*16+l15
  bf16x8 qf[2][8];
#pragma unroll
  for (int im = 0; im < 2; ++im) {
    const unsigned short* qrow =
        qp + base + (size_t)(q0 + qh * 32 + im * 16 + l15) * DIMQ;
#pragma unroll
    for (int s = 0; s < 8; ++s)
      qf[im][s] = *(const bf16x8*)(qrow + s * 32 + quad * 8);
  }

  f32x4 oacc[4][4] = {};   // O rows mt*16+quad*4+r, cols wave*64+nt*16+l15
  float lrow[2][4] = {};

  const unsigned short* kb = kp + (size_t)b * LKV * KSTR + h * HD;   // stride KSTR
  const unsigned short* vtb = vpT + ((size_t)b * DIMQ + h * HD) * LKV;

  const int krow_l = lane >> 5;   // K stage: 2 rows (512B) per 1KB chunk
  const int kcol_l = lane & 31;
  const int vrow_l = lane >> 3;   // V stage: 8 rows (128B) per 1KB chunk
  const int vcol_l = lane & 7;

  // prologue: stage K tile 0 (row-permuted source)
#pragma unroll
  for (int i = 0; i < 8; ++i) {
    int c = i * 4 + wave;
    int row = 2 * c + krow_l;                                  // LDS row
    int lr = (row & 32) + ((row & 15) << 1) + ((row >> 4) & 1); // logical kv
    gl2lds16(kb + (size_t)lr * KSTR + ((kcol_l ^ (row & 7)) << 3), Ks + c * 512);
  }
  __syncthreads();

  for (int kv0 = 0; kv0 < LKV; kv0 += 64) {
    // stage V(t): latency hides under QK + softmax
#pragma unroll
    for (int i = 0; i < 8; ++i) {
      int c = i * 4 + wave;
      int row = 8 * c + vrow_l;
      gl2lds16(vtb + (size_t)row * LKV + kv0 + ((vcol_l ^ (row & 7)) << 3),
               Vt + c * 512);
    }

    // QK: S 32q x 32kv per wave (2m x 2n), Q from regs
    f32x4 sacc[2][2] = {};
    const int r0 = kvh * 32 + l15, r1 = r0 + 16;
    __builtin_amdgcn_s_setprio(1);
#pragma unroll
    for (int s = 0; s < 8; ++s) {
      bf16x8 kf0 = *(const bf16x8*)(Ks + r0 * 256 + (((s * 4 + quad) ^ (r0 & 7)) << 3));
      bf16x8 kf1 = *(const bf16x8*)(Ks + r1 * 256 + (((s * 4 + quad) ^ (r1 & 7)) << 3));
      sacc[0][0] = __builtin_amdgcn_mfma_f32_16x16x32_bf16(qf[0][s], kf0, sacc[0][0], 0, 0, 0);
      sacc[0][1] = __builtin_amdgcn_mfma_f32_16x16x32_bf16(qf[0][s], kf1, sacc[0][1], 0, 0, 0);
      sacc[1][0] = __builtin_amdgcn_mfma_f32_16x16x32_bf16(qf[1][s], kf0, sacc[1][0], 0, 0, 0);
      sacc[1][1] = __builtin_amdgcn_mfma_f32_16x16x32_bf16(qf[1][s], kf1, sacc[1][1], 0, 0, 0);
    }
    __builtin_amdgcn_s_setprio(0);

    // p = exp2(s); sacc[..][0]=col 2*l15, sacc[..][1]=col 2*l15+1 (adjacent)
    // -> one packed dword write per (im,i).
    const int dw = kvh * 16 + l15;       // dword index within row
    const int t16 = dw >> 2, sub = dw & 3;
#pragma unroll
    for (int im = 0; im < 2; ++im)
#pragma unroll
      for (int i = 0; i < 4; ++i) {
        int row = qh * 32 + im * 16 + quad * 4 + i;
        float p0 = exp2f(sacc[im][0][i]);
        float p1 = exp2f(sacc[im][1][i]);
        unsigned pw = (unsigned)f32_to_bf16(p0) | ((unsigned)f32_to_bf16(p1) << 16);
        *(unsigned*)(Ps + row * 64 + (((t16 ^ (row & 7)) << 3) | (sub * 2))) = pw;
        lrow[im][i] += p0 + p1;
      }
    __syncthreads();   // V(t) staged + P visible block-wide

    // stage K(t+1): latency hides under PV (row-permuted source)
    if (kv0 + 64 < LKV) {
#pragma unroll
      for (int i = 0; i < 8; ++i) {
        int c = i * 4 + wave;
        int row = 2 * c + krow_l;
        int lr = (row & 32) + ((row & 15) << 1) + ((row >> 4) & 1);
        gl2lds16(kb + (size_t)(kv0 + 64 + lr) * KSTR + ((kcol_l ^ (row & 7)) << 3),
                 Ks + c * 512);
      }
    }

    // PV: O 64q x 64d per wave (4m x 4n), every fragment feeds 4 MFMAs
    __builtin_amdgcn_s_setprio(1);
#pragma unroll
    for (int u = 0; u < 2; ++u) {
      bf16x8 pf[4], vf[4];
#pragma unroll
      for (int mt = 0; mt < 4; ++mt) {
        int pr = mt * 16 + l15;
        pf[mt] = *(const bf16x8*)(Ps + pr * 64 + (((u * 4 + quad) ^ (pr & 7)) << 3));
      }
#pragma unroll
      for (int nt = 0; nt < 4; ++nt) {
        int vr = wave * 64 + nt * 16 + l15;
        vf[nt] = *(const bf16x8*)(Vt + vr * 64 + (((u * 4 + quad) ^ (vr & 7)) << 3));
      }
#pragma unroll
      for (int mt = 0; mt < 4; ++mt)
#pragma unroll
        for (int nt = 0; nt < 4; ++nt)
          oacc[mt][nt] = __builtin_amdgcn_mfma_f32_16x16x32_bf16(pf[mt], vf[nt], oacc[mt][nt], 0, 0, 0);
    }
    __builtin_amdgcn_s_setprio(0);
    __syncthreads();   // K(t+1) staged; PV readers done
  }

  // epilogue: reduce l over l15 lanes, then cross-wave (kv halves) via Ls
#pragma unroll
  for (int im = 0; im < 2; ++im)
#pragma unroll
    for (int i = 0; i < 4; ++i) {
      float l = lrow[im][i];
      l += __shfl_xor(l, 1);
      l += __shfl_xor(l, 2);
      l += __shfl_xor(l, 4);
      l += __shfl_xor(l, 8);
      if (l15 == 0) Ls[qh * 32 + im * 16 + quad * 4 + i][kvh] = l;
    }
  __syncthreads();

  unsigned short* cb = ctx + base;
#pragma unroll
  for (int mt = 0; mt < 4; ++mt)
#pragma unroll
    for (int r = 0; r < 4; ++r) {
      int row = mt * 16 + quad * 4 + r;
      float inv = 1.0f / (Ls[row][0] + Ls[row][1]);
#pragma unroll
      for (int nt = 0; nt < 4; ++nt) {
        int col = wave * 64 + nt * 16 + l15;
        cb[(size_t)(q0 + row) * DIMQ + col] = f32_to_bf16(oacc[mt][nt][r] * inv);
      }
    }
}

extern "C" void kernel_launch(void* const* d_in, const int* in_sizes, int n_in,
                              void* d_out, int out_size, void* d_ws, size_t ws_size,
                              hipStream_t stream) {
  const float* q  = (const float*)d_in[0];
  const float* kv = (const float*)d_in[1];
  const float* Wq = (const float*)d_in[2];
  const float* Wk = (const float*)d_in[3];
  const float* Wv = (const float*)d_in[4];
  const float* Wo = (const float*)d_in[5];
  const float* bo = (const float*)d_in[6];
  float* out = (float*)d_out;

  const long NQ = (long)BSZ * LQ * DIMQ;       // 8388608
  const long NKV = (long)BSZ * LKV * 768;      // 6291456
  const long NWQ = (long)DIMQ * DIMQ;          // 1048576
  const long NWK = (long)DIMQ * 768;           // 786432

  // d_out phases: q_bf (16 MB) -> kp [8192][1024] (16 MB, overwrites q_bf
  // after qp GEMM) -> final fp32 out (32 MB, after attn).
  unsigned short* q_bf = (unsigned short*)d_out;
  unsigned short* kp   = (unsigned short*)d_out;
  // ws (58 MB): [kv_bf|ctx 16MB][Wq 2][Wk 1.5][Wv 1.5][Wo 2][qp 16][vpT 16]
  unsigned short* kv_bf = (unsigned short*)d_ws;
  unsigned short* ctx   = kv_bf;                           // kv_bf dead after vpT GEMM
  unsigned short* Wq_bf = kv_bf + NQ;
  unsigned short* Wk_bf = Wq_bf + NWQ;
  unsigned short* Wv_bf = Wk_bf + NWK;
  unsigned short* Wo_bf = Wv_bf + NWK;
  unsigned short* qp    = Wo_bf + NWQ;
  unsigned short* vpT   = qp + NQ;               // [BSZ][DIMQ][LKV] = 16 MB

  dim3 blk(256);
  const int M = BSZ * LQ;  // 8192

  // 1) convert q + kv + weights. Wq scale folds 1/16 (sqrt(hd)) AND log2(e)
  //    (softmax computed in exp2 domain).
  cvt6<<<dim3(4096, 6), blk, 0, stream>>>(
      kv, Wq, Wk, Wv, Wo, q,
      kv_bf, Wq_bf, Wk_bf, Wv_bf, Wo_bf, q_bf,
      NKV, NWQ, NWK, NWK, NWQ, NQ,
      1.0f, 0.0625f * 1.44269504088896f, 1.0f, 1.0f, 1.0f, 1.0f);
  // 2) qp = q_bf Wq^T (reads d_out, writes ws). nwg=512.
  gemm_bt<unsigned short, false><<<dim3((M/128)*(DIMQ/128)), blk, 0, stream>>>(q_bf, Wq_bf, nullptr, qp, M, DIMQ, 1024);
  // 3) kp = kv_bf Wk^T (overwrites q_bf - dead). nwg=512.
  gemm_bt<unsigned short, false><<<dim3((M/128)*(DIMQ/128)), blk, 0, stream>>>(kv_bf, Wk_bf, nullptr, kp, M, DIMQ, 768);
  // 4) vpT[b][d][l] = sum_k Wv[d,k] kv_bf[b*2048+l,k]  (BATCH_OUT epilogue;
  //    replaces transpose kernel, R3-identical layout). M=1024,N=8192,nwg=512.
  gemm_bt<unsigned short, false, true><<<dim3((DIMQ/128)*(M/128)), blk, 0, stream>>>(Wv_bf, kv_bf, nullptr, vpT, DIMQ, M, 768);
  // 5) attention -> ctx (kv_bf slot, dead)
  attn<<<dim3(512), blk, 0, stream>>>(qp, kp, vpT, ctx);
  // 6) out = ctx Wo^T + bo (fp32, overwrites kp - dead)
  gemm_bt<float, true><<<dim3((M/128)*(DIMQ/128)), blk, 0, stream>>>(ctx, Wo_bf, bo, out, M, DIMQ, 1024);
}